// Round 1
// baseline (223.802 us; speedup 1.0000x reference)
//
#include <hip/hip_runtime.h>
#include <math.h>

#define NEXP 8
#define DIN 128
#define ISZ 16
#define TT 8                    // tokens per wave
#define NWAVE 4
#define TOK_PER_BLK (TT * NWAVE)  // 32
#define NTOK (16 * 4096)          // 65536

#define DPAD 132                           // padded D stride for transposed w1
#define W1T_ESTR (ISZ * DPAD + 4)          // 2116 floats per expert (bank-spread)

#define LDS_W1T (NEXP * W1T_ESTR)          // 16928 floats
#define LDS_W2  (NEXP * ISZ * DIN)         // 16384 floats
#define LDS_X   (TOK_PER_BLK * DIN)        // 4096 floats
#define LDS_RW  (TOK_PER_BLK * NEXP)       // 256 floats
#define LDS_FLOATS (LDS_W1T + LDS_W2 + LDS_X + LDS_RW)
#define SMEM_BYTES (LDS_FLOATS * 4)        // 150656 bytes (< 160 KiB)

__global__ __launch_bounds__(256, 1) void moe_fused_kernel(
    const float* __restrict__ x,
    const float* __restrict__ rw,
    const float* __restrict__ w1,
    const float* __restrict__ w2,
    float* __restrict__ out_agg,
    float* __restrict__ out_exp)
{
    extern __shared__ float lds[];
    float* w1t = lds;                 // [E][I][DPAD] transposed w1
    float* w2s = w1t + LDS_W1T;       // [E][I][D]
    float* xs  = w2s + LDS_W2;        // [32 tok][D]  (becomes gy after GEMM1)
    float* rws = xs + LDS_X;          // [32 tok][E]

    const int tid  = threadIdx.x;
    const int wave = tid >> 6;
    const int lane = tid & 63;
    const int btok = blockIdx.x * TOK_PER_BLK;

    // ---- stage w1 transposed: w1[e][c][i] -> w1t[e][i][c] ----
    for (int idx = tid; idx < NEXP * DIN * ISZ; idx += 256) {
        int e = idx >> 11;
        int r = idx & 2047;
        int c = r >> 4;
        int i = r & 15;
        w1t[e * W1T_ESTR + i * DPAD + c] = w1[idx];
    }
    // ---- stage w2 straight (float4) ----
    {
        const float4* src = (const float4*)w2;
        float4* dst = (float4*)w2s;
        for (int idx = tid; idx < (NEXP * ISZ * DIN) / 4; idx += 256)
            dst[idx] = src[idx];
    }
    // ---- stage x for this block's 32 tokens (float4, coalesced) ----
    {
        const float4* src = (const float4*)(x + (size_t)btok * DIN);
        float4* dst = (float4*)xs;
        for (int idx = tid; idx < (TOK_PER_BLK * DIN) / 4; idx += 256)
            dst[idx] = src[idx];
    }
    // ---- stage routing weights: exactly 256 floats ----
    rws[tid] = rw[(size_t)btok * NEXP + tid];
    __syncthreads();

    float* xw = xs + wave * TT * DIN;            // this wave's 8 tokens
    const float* rww = rws + wave * TT * NEXP;

    // ================= GEMM1: y[t][e][i] = x . w1 =================
    // lane -> (e1 = lane>>3, g = lane&7); computes i = 2g, 2g+1
    const int e1 = lane >> 3;
    const int g  = lane & 7;
    float y0[TT], y1[TT];
#pragma unroll
    for (int t = 0; t < TT; ++t) { y0[t] = 0.f; y1[t] = 0.f; }

    const float* w1a = w1t + e1 * W1T_ESTR + (2 * g) * DPAD;
    const float* w1b = w1a + DPAD;
    for (int c4 = 0; c4 < DIN / 4; ++c4) {
        float4 wa = *(const float4*)(w1a + c4 * 4);
        float4 wb = *(const float4*)(w1b + c4 * 4);
#pragma unroll
        for (int t = 0; t < TT; ++t) {
            float4 xv = *(const float4*)(xw + t * DIN + c4 * 4);  // broadcast
            y0[t] += xv.x * wa.x + xv.y * wa.y + xv.z * wa.z + xv.w * wa.w;
            y1[t] += xv.x * wb.x + xv.y * wb.y + xv.z * wb.z + xv.w * wb.w;
        }
    }

    // ---- exact GELU, write gy over the x slot ----
#pragma unroll
    for (int t = 0; t < TT; ++t) {
        float a = y0[t], b = y1[t];
        a = 0.5f * a * (1.f + erff(a * 0.70710678118654752f));
        b = 0.5f * b * (1.f + erff(b * 0.70710678118654752f));
        float2 v = make_float2(a, b);
        *(float2*)(xw + t * DIN + e1 * ISZ + 2 * g) = v;
    }
    __syncthreads();

    // ================= GEMM2 + weighted agg =================
    // lane -> c4 = lane&31 (channel quad), h = lane>>5 (expert parity)
    const int c4 = lane & 31;
    const int h  = lane >> 5;
    float agg[TT][4];
#pragma unroll
    for (int t = 0; t < TT; ++t) {
        agg[t][0] = 0.f; agg[t][1] = 0.f; agg[t][2] = 0.f; agg[t][3] = 0.f;
    }

#pragma unroll
    for (int k = 0; k < 4; ++k) {
        const int e = 2 * k + h;
        float acc[TT][4];
#pragma unroll
        for (int t = 0; t < TT; ++t) {
            acc[t][0] = 0.f; acc[t][1] = 0.f; acc[t][2] = 0.f; acc[t][3] = 0.f;
        }
        const float* w2e = w2s + e * ISZ * DIN + c4 * 4;
#pragma unroll
        for (int i = 0; i < ISZ; ++i) {
            float4 wv = *(const float4*)(w2e + i * DIN);
#pragma unroll
            for (int t = 0; t < TT; ++t) {
                float gv = xw[t * DIN + e * ISZ + i];   // broadcast within half-wave
                acc[t][0] += gv * wv.x;
                acc[t][1] += gv * wv.y;
                acc[t][2] += gv * wv.z;
                acc[t][3] += gv * wv.w;
            }
        }
#pragma unroll
        for (int t = 0; t < TT; ++t) {
            const int gtok = btok + wave * TT + t;
            float4 v = make_float4(acc[t][0], acc[t][1], acc[t][2], acc[t][3]);
            *(float4*)(out_exp + (size_t)gtok * (NEXP * DIN) + e * DIN + c4 * 4) = v;
            float r = rww[t * NEXP + e];
            agg[t][0] += r * acc[t][0];
            agg[t][1] += r * acc[t][1];
            agg[t][2] += r * acc[t][2];
            agg[t][3] += r * acc[t][3];
        }
    }

    // combine expert parities: lane l (+) lane l^32, then lanes 0..31 write
#pragma unroll
    for (int t = 0; t < TT; ++t) {
#pragma unroll
        for (int j = 0; j < 4; ++j)
            agg[t][j] += __shfl_xor(agg[t][j], 32);
    }
    if (h == 0) {
#pragma unroll
        for (int t = 0; t < TT; ++t) {
            const int gtok = btok + wave * TT + t;
            *(float4*)(out_agg + (size_t)gtok * DIN + c4 * 4) =
                make_float4(agg[t][0], agg[t][1], agg[t][2], agg[t][3]);
        }
    }
}

extern "C" void kernel_launch(void* const* d_in, const int* in_sizes, int n_in,
                              void* d_out, int out_size, void* d_ws, size_t ws_size,
                              hipStream_t stream) {
    const float* x  = (const float*)d_in[0];
    const float* rw = (const float*)d_in[1];
    const float* w1 = (const float*)d_in[2];
    const float* w2 = (const float*)d_in[3];

    float* out_agg = (float*)d_out;                       // [NTOK][128]
    float* out_exp = out_agg + (size_t)NTOK * DIN;        // [NTOK][8][128]

    // opt in to >64KB dynamic LDS (ignore result; plain launch works on most ROCm)
    (void)hipFuncSetAttribute((const void*)moe_fused_kernel,
                              hipFuncAttributeMaxDynamicSharedMemorySize,
                              SMEM_BYTES);

    dim3 grid(NTOK / TOK_PER_BLK);   // 2048
    dim3 block(256);
    moe_fused_kernel<<<grid, block, SMEM_BYTES, stream>>>(
        x, rw, w1, w2, out_agg, out_exp);
}